// Round 1
// 599.732 us; speedup vs baseline: 1.0455x; 1.0455x over previous
//
#include <hip/hip_runtime.h>

#define N_NODES 100000
#define M_PAD   100096      // N_NODES rounded up to BM multiple (pad rows: garbage, never stored)
#define N_EDGES 1000000
#define K_TOT   320         // 128 (x) + 128 (agg_x) + 64 (agg_t)
#define NCHUNK  98          // ceil(100000/1024)

#define BM  128
#define LDA 72              // padded LDS row stride (bf16 elems)

#define XCONV_THREADS 1600000   // N_NODES*128/8 elems, 8 per thread

typedef __attribute__((ext_vector_type(8))) short bf16x8;
typedef __attribute__((ext_vector_type(4))) float f32x4;

__device__ __forceinline__ unsigned short f2bf(float f) {
    unsigned u = __float_as_uint(f);
    u += 0x7FFFu + ((u >> 16) & 1u);          // round-to-nearest-even
    return (unsigned short)(u >> 16);
}
__device__ __forceinline__ unsigned pack2(float a, float b) {
    return (unsigned)f2bf(a) | ((unsigned)f2bf(b) << 16);
}

// ---------------------------------------------------------------------------
// Prep (fused): xb = bf16(x)  AND  Gtb[o][k] (k-contig bf16)  AND  bias2.
// Rounding here is identical to what the old GEMM staging did -> bit-identical.
// ---------------------------------------------------------------------------
__global__ __launch_bounds__(256) void prep_kernel(
        const float* __restrict__ x,
        const float* __restrict__ WSw,
        const float* __restrict__ WTw,
        const float* __restrict__ Tw,
        const float* __restrict__ WTb,
        const float* __restrict__ Tb,
        unsigned short* __restrict__ xb,
        unsigned short* __restrict__ Gtb,
        float* __restrict__ bias2) {
    int gid = blockIdx.x * 256 + threadIdx.x;
    if (gid < XCONV_THREADS) {
        const float4* p = (const float4*)x + (size_t)gid * 2;
        float4 u0 = p[0], u1 = p[1];
        uint4 w;
        w.x = pack2(u0.x, u0.y);
        w.y = pack2(u0.z, u0.w);
        w.z = pack2(u1.x, u1.y);
        w.w = pack2(u1.z, u1.w);
        *(uint4*)(xb + (size_t)gid * 8) = w;
    } else {
        int idx = gid - XCONV_THREADS;
        if (idx < K_TOT * 128) {
            int k = idx >> 7;
            int o = idx & 127;
            float v = (k < 128) ? WSw[o * 128 + k]
                    : (k < 256) ? WTw[o * 128 + (k - 128)]
                                : Tw[o * 64 + (k - 256)];
            Gtb[(size_t)o * K_TOT + k] = f2bf(v);
        }
        if (idx < 128) bias2[idx] = WTb[idx] + Tb[idx];
    }
}

// ---------------------------------------------------------------------------
// CSR build: histogram -> scan -> fill ec[pos] = (col,e)
// fill bumps `offsets` in place; afterwards offsets[n] == end[n] and
// offsets[n-1] == beg[n] (CSR contiguity) -> no cursor copy needed.
// ---------------------------------------------------------------------------
__global__ __launch_bounds__(256) void hist_kernel(const int* __restrict__ ei,
                                                   int* __restrict__ hist) {
    int e = blockIdx.x * 256 + threadIdx.x;
    if (e < N_EDGES) atomicAdd(&hist[ei[e]], 1);
}

__global__ __launch_bounds__(256) void scan_pass1(const int* __restrict__ hist,
                                                  int* __restrict__ chunksum) {
    __shared__ int ts[256];
    int b = blockIdx.x, t = threadIdx.x;
    int i = b * 1024 + t * 4;
    int s = 0;
#pragma unroll
    for (int j = 0; j < 4; ++j)
        if (i + j < N_NODES) s += hist[i + j];
    ts[t] = s;
    __syncthreads();
    for (int off = 128; off > 0; off >>= 1) {
        if (t < off) ts[t] += ts[t + off];
        __syncthreads();
    }
    if (t == 0) chunksum[b] = ts[0];
}

__global__ __launch_bounds__(128) void scan_mid(const int* __restrict__ chunksum,
                                                int* __restrict__ chunkoff) {
    __shared__ int ts[128];
    int t = threadIdx.x;
    int v = (t < NCHUNK) ? chunksum[t] : 0;
    ts[t] = v;
    __syncthreads();
    for (int off = 1; off < 128; off <<= 1) {
        int a = (t >= off) ? ts[t - off] : 0;
        __syncthreads();
        ts[t] += a;
        __syncthreads();
    }
    if (t < NCHUNK) chunkoff[t] = ts[t] - v;   // exclusive
}

__global__ __launch_bounds__(256) void scan_pass2(const int* __restrict__ hist,
                                                  const int* __restrict__ chunkoff,
                                                  int* __restrict__ offsets) {
    __shared__ int ts[256];
    int b = blockIdx.x, t = threadIdx.x;
    int i0 = b * 1024 + t * 4;
    int v[4];
    int s = 0;
#pragma unroll
    for (int j = 0; j < 4; ++j) {
        v[j] = (i0 + j < N_NODES) ? hist[i0 + j] : 0;
        s += v[j];
    }
    ts[t] = s;
    __syncthreads();
    for (int off = 1; off < 256; off <<= 1) {
        int add = (t >= off) ? ts[t - off] : 0;
        __syncthreads();
        ts[t] += add;
        __syncthreads();
    }
    int run = chunkoff[b] + ts[t] - s;   // exclusive base for this thread
#pragma unroll
    for (int j = 0; j < 4; ++j) {
        if (i0 + j < N_NODES) offsets[i0 + j] = run;
        run += v[j];
    }
}

__global__ __launch_bounds__(256) void fill_kernel(const int* __restrict__ ei,
                                                   int* __restrict__ offsets,
                                                   unsigned long long* __restrict__ ec) {
    int e = blockIdx.x * 256 + threadIdx.x;
    if (e < N_EDGES) {
        int row = ei[e];
        int col = ei[N_EDGES + e];
        int pos = atomicAdd(&offsets[row], 1);
        ec[pos] = ((unsigned long long)(unsigned)col << 32) | (unsigned)e;
    }
}

// ---------------------------------------------------------------------------
// Segment reduce: one wave per node, 4 edges per iteration.
// Accumulates fp32 (same per-column summation tree as before), emits bf16
// (same f2bf the GEMM used to apply) -> bit-identical output, half the bytes.
// x gathered as float2/lane: lane holds cols (2l, 2l+1) -> shuffle-free pack.
// ---------------------------------------------------------------------------
__global__ __launch_bounds__(256) void agg_kernel(
        const float* __restrict__ x,
        const float* __restrict__ tf,
        const unsigned long long* __restrict__ ec,
        const int* __restrict__ offsets,   // post-fill: offsets[n] = end[n]
        unsigned* __restrict__ aggxb,      // u32 view: row stride 64 words (128 bf16)
        unsigned* __restrict__ aggtb,      // u32 view: row stride 32 words (64 bf16)
        float* __restrict__ deg) {
    int lane = threadIdx.x & 63;
    int n = blockIdx.x * 4 + (threadIdx.x >> 6);
    if (n >= N_NODES) return;

    int beg = n ? offsets[n - 1] : 0;
    int end = offsets[n];

    float ax = 0.f, ay = 0.f, at = 0.f;
    float bx = 0.f, by = 0.f, bt = 0.f;

    int i = beg;
    for (; i + 3 < end; i += 4) {
        unsigned long long p0 = ec[i],     p1 = ec[i + 1];
        unsigned long long p2 = ec[i + 2], p3 = ec[i + 3];
        const float2* x0p = (const float2*)(x + ((size_t)(p0 >> 32) << 7)) + lane;
        const float2* x1p = (const float2*)(x + ((size_t)(p1 >> 32) << 7)) + lane;
        const float2* x2p = (const float2*)(x + ((size_t)(p2 >> 32) << 7)) + lane;
        const float2* x3p = (const float2*)(x + ((size_t)(p3 >> 32) << 7)) + lane;
        const float* t0p = tf + ((size_t)(unsigned)p0 << 6);
        const float* t1p = tf + ((size_t)(unsigned)p1 << 6);
        const float* t2p = tf + ((size_t)(unsigned)p2 << 6);
        const float* t3p = tf + ((size_t)(unsigned)p3 << 6);
        float2 a = *x0p, b = *x1p, c = *x2p, d = *x3p;
        float u0 = __builtin_nontemporal_load(t0p + lane);
        float u1 = __builtin_nontemporal_load(t1p + lane);
        float u2 = __builtin_nontemporal_load(t2p + lane);
        float u3 = __builtin_nontemporal_load(t3p + lane);
        ax += a.x; ay += a.y; at += u0;
        bx += b.x; by += b.y; bt += u1;
        ax += c.x; ay += c.y; at += u2;
        bx += d.x; by += d.y; bt += u3;
    }
    for (; i < end; ++i) {
        unsigned long long p0 = ec[i];
        float2 a = *((const float2*)(x + ((size_t)(p0 >> 32) << 7)) + lane);
        ax += a.x; ay += a.y;
        at += __builtin_nontemporal_load(tf + ((size_t)(unsigned)p0 << 6) + lane);
    }

    float fx = ax + bx, fy = ay + by, ft = at + bt;
    aggxb[(size_t)n * 64 + lane] = pack2(fx, fy);        // cols 2l, 2l+1
    float pt = __shfl_xor(ft, 1);
    if (!(lane & 1))
        aggtb[(size_t)n * 32 + (lane >> 1)] = pack2(ft, pt);  // cols l, l+1
    if (lane == 0) deg[n] = (float)(end - beg);
}

// ---------------------------------------------------------------------------
// MFMA bf16 GEMM: out = relu([xb | aggxb | aggtb] @ Gtb^T + WSb + deg*bias2)
// All operands pre-converted bf16 -> staging is a pure uint4 copy (no VALU
// pack). Rows >= N_NODES read padded workspace garbage; their acc rows are
// never stored.
// ---------------------------------------------------------------------------
__global__ __launch_bounds__(256) void gemm_kernel(
        const unsigned short* __restrict__ xb,
        const unsigned short* __restrict__ aggxb,
        const unsigned short* __restrict__ aggtb,
        const unsigned short* __restrict__ Gtb,
        const float* __restrict__ WSb,
        const float* __restrict__ bias2,
        const float* __restrict__ deg,
        float* __restrict__ out) {
    __shared__ unsigned short As[BM * LDA];
    __shared__ unsigned short Bs[BM * LDA];

    int t = threadIdx.x;
    int lane = t & 63;
    int wave = t >> 6;
    int mw = (wave & 1) * 64;
    int nw = (wave >> 1) * 64;
    int row0 = blockIdx.x * BM;
    int quad = lane >> 4;
    int l16  = lane & 15;

    f32x4 acc[4][4];
#pragma unroll
    for (int mt = 0; mt < 4; ++mt)
#pragma unroll
        for (int nt = 0; nt < 4; ++nt)
            acc[mt][nt] = (f32x4){0.f, 0.f, 0.f, 0.f};

    int sm = t >> 1;            // staging row 0..127
    int sh = (t & 1) * 32;      // staging k-half offset (bf16 elems)

    for (int c = 0; c < 5; ++c) {
        const unsigned short* src; int ld, koff;
        if (c < 2)      { src = xb;    ld = 128; koff = c * 64; }
        else if (c < 4) { src = aggxb; ld = 128; koff = (c - 2) * 64; }
        else            { src = aggtb; ld = 64;  koff = 0; }

        // issue global loads before the barrier: overlap with prev MFMA
        const unsigned short* ap = src + (size_t)(row0 + sm) * ld + koff + sh;
        uint4 a0 = *(const uint4*)(ap);
        uint4 a1 = *(const uint4*)(ap + 8);
        uint4 a2 = *(const uint4*)(ap + 16);
        uint4 a3 = *(const uint4*)(ap + 24);
        const unsigned short* gp = Gtb + (size_t)sm * K_TOT + c * 64 + sh;
        uint4 b0 = *(const uint4*)(gp);
        uint4 b1 = *(const uint4*)(gp + 8);
        uint4 b2 = *(const uint4*)(gp + 16);
        uint4 b3 = *(const uint4*)(gp + 24);

        __syncthreads();        // previous iteration's LDS reads done

        *(uint4*)&As[sm * LDA + sh]      = a0;
        *(uint4*)&As[sm * LDA + sh + 8]  = a1;
        *(uint4*)&As[sm * LDA + sh + 16] = a2;
        *(uint4*)&As[sm * LDA + sh + 24] = a3;
        *(uint4*)&Bs[sm * LDA + sh]      = b0;
        *(uint4*)&Bs[sm * LDA + sh + 8]  = b1;
        *(uint4*)&Bs[sm * LDA + sh + 16] = b2;
        *(uint4*)&Bs[sm * LDA + sh + 24] = b3;

        __syncthreads();

#pragma unroll
        for (int ks = 0; ks < 2; ++ks) {
            bf16x8 af[4], bfv[4];
#pragma unroll
            for (int mt = 0; mt < 4; ++mt)
                af[mt] = *(bf16x8*)&As[(mw + mt * 16 + l16) * LDA + ks * 32 + quad * 8];
#pragma unroll
            for (int nt = 0; nt < 4; ++nt)
                bfv[nt] = *(bf16x8*)&Bs[(nw + nt * 16 + l16) * LDA + ks * 32 + quad * 8];
#pragma unroll
            for (int mt = 0; mt < 4; ++mt)
#pragma unroll
                for (int nt = 0; nt < 4; ++nt)
                    acc[mt][nt] = __builtin_amdgcn_mfma_f32_16x16x32_bf16(
                        af[mt], bfv[nt], acc[mt][nt], 0, 0, 0);
        }
    }

    // epilogue: bias + deg*bias2 + ReLU
#pragma unroll
    for (int mt = 0; mt < 4; ++mt) {
#pragma unroll
        for (int r = 0; r < 4; ++r) {
            int m = row0 + mw + mt * 16 + quad * 4 + r;
            if (m >= N_NODES) continue;
            float dg = deg[m];
#pragma unroll
            for (int nt = 0; nt < 4; ++nt) {
                int o = nw + nt * 16 + l16;
                float val = acc[mt][nt][r] + WSb[o] + dg * bias2[o];
                out[(size_t)m * 128 + o] = fmaxf(val, 0.f);
            }
        }
    }
}

// ---------------------------------------------------------------------------
extern "C" void kernel_launch(void* const* d_in, const int* in_sizes, int n_in,
                              void* d_out, int out_size, void* d_ws, size_t ws_size,
                              hipStream_t stream) {
    const float* x   = (const float*)d_in[0];
    const int*   ei  = (const int*)d_in[1];
    const float* tf  = (const float*)d_in[2];
    const float* WSw = (const float*)d_in[3];
    const float* WSb = (const float*)d_in[4];
    const float* WTw = (const float*)d_in[5];
    const float* WTb = (const float*)d_in[6];
    const float* Tw  = (const float*)d_in[7];
    const float* Tb  = (const float*)d_in[8];
    float* out = (float*)d_out;

    // Workspace layout (~73.4 MB), 16B-aligned blocks first:
    unsigned short* xb    = (unsigned short*)d_ws;                 // M_PAD*128 bf16
    unsigned short* aggxb = xb    + (size_t)M_PAD * 128;           // M_PAD*128 bf16
    unsigned short* aggtb = aggxb + (size_t)M_PAD * 128;           // M_PAD*64  bf16
    unsigned short* Gtb   = aggtb + (size_t)M_PAD * 64;            // 320*128   bf16
    unsigned long long* ec = (unsigned long long*)(Gtb + (size_t)K_TOT * 128); // 1M u64
    float* deg   = (float*)(ec + N_EDGES);                         // 100000 f
    float* bias2 = deg + N_NODES;                                  // 128 f
    int* hist    = (int*)(bias2 + 128);                            // 100000 i
    int* offsets = hist + N_NODES;                                 // 100002 i
    int* csum    = offsets + (N_NODES + 2);                        // 128 i
    int* coff    = csum + 128;                                     // 128 i

    hipMemsetAsync(hist, 0, (size_t)N_NODES * sizeof(int), stream);

    prep_kernel<<<(XCONV_THREADS + K_TOT * 128) / 256, 256, 0, stream>>>(
        x, WSw, WTw, Tw, WTb, Tb, xb, Gtb, bias2);

    hist_kernel<<<(N_EDGES + 255) / 256, 256, 0, stream>>>(ei, hist);
    scan_pass1<<<NCHUNK, 256, 0, stream>>>(hist, csum);
    scan_mid<<<1, 128, 0, stream>>>(csum, coff);
    scan_pass2<<<NCHUNK, 256, 0, stream>>>(hist, coff, offsets);

    fill_kernel<<<(N_EDGES + 255) / 256, 256, 0, stream>>>(ei, offsets, ec);

    agg_kernel<<<N_NODES / 4, 256, 0, stream>>>(
        x, tf, ec, offsets, (unsigned*)aggxb, (unsigned*)aggtb, deg);

    gemm_kernel<<<(N_NODES + BM - 1) / BM, 256, 0, stream>>>(
        xb, aggxb, aggtb, Gtb, WSb, bias2, deg, out);
}

// Round 2
// 575.852 us; speedup vs baseline: 1.0889x; 1.0415x over previous
//
#include <hip/hip_runtime.h>

#define N_NODES 100000
#define M_PAD   100096      // N_NODES rounded up to BM multiple (pad rows: garbage, never stored)
#define N_EDGES 1000000
#define K_TOT   320         // 128 (x) + 128 (agg_x) + 64 (agg_t)
#define NCHUNK  98          // ceil(100000/1024)

#define BM  128
#define LDA 72              // padded LDS row stride (bf16 elems)

#define XCONV_THREADS 1600000          // N_NODES*128/8 elems, 8 per thread
#define PREP_BLOCKS   6410             // (XCONV_THREADS + K_TOT*128)/256
#define HIST_BLOCKS   3907             // ceil(N_EDGES/256)

typedef __attribute__((ext_vector_type(8))) short bf16x8;
typedef __attribute__((ext_vector_type(4))) float f32x4;

__device__ __forceinline__ unsigned short f2bf(float f) {
    unsigned u = __float_as_uint(f);
    u += 0x7FFFu + ((u >> 16) & 1u);          // round-to-nearest-even
    return (unsigned short)(u >> 16);
}
__device__ __forceinline__ unsigned pack2(float a, float b) {
    return (unsigned)f2bf(a) | ((unsigned)f2bf(b) << 16);
}
__device__ __forceinline__ float bflo(unsigned v) { return __uint_as_float(v << 16); }
__device__ __forceinline__ float bfhi(unsigned v) { return __uint_as_float(v & 0xffff0000u); }

// ---------------------------------------------------------------------------
// Fused prep + hist:
//   blocks [0, PREP_BLOCKS):  xb = bf16(x), Gtb[o][k] k-contig bf16, bias2
//   blocks [PREP_BLOCKS, +HIST_BLOCKS): edge histogram (hist pre-zeroed)
// prep is BW-bound streaming, hist is atomic-bound -> good overlap.
// ---------------------------------------------------------------------------
__global__ __launch_bounds__(256) void prep_hist_kernel(
        const float* __restrict__ x,
        const float* __restrict__ WSw,
        const float* __restrict__ WTw,
        const float* __restrict__ Tw,
        const float* __restrict__ WTb,
        const float* __restrict__ Tb,
        unsigned short* __restrict__ xb,
        unsigned short* __restrict__ Gtb,
        float* __restrict__ bias2,
        const int* __restrict__ ei,
        int* __restrict__ hist) {
    int b = blockIdx.x;
    int t = threadIdx.x;
    if (b >= PREP_BLOCKS) {
        int e = (b - PREP_BLOCKS) * 256 + t;
        if (e < N_EDGES) atomicAdd(&hist[ei[e]], 1);
        return;
    }
    int gid = b * 256 + t;
    if (gid < XCONV_THREADS) {
        const float4* p = (const float4*)x + (size_t)gid * 2;
        float4 u0 = p[0], u1 = p[1];
        uint4 w;
        w.x = pack2(u0.x, u0.y);
        w.y = pack2(u0.z, u0.w);
        w.z = pack2(u1.x, u1.y);
        w.w = pack2(u1.z, u1.w);
        *(uint4*)(xb + (size_t)gid * 8) = w;
    } else {
        int idx = gid - XCONV_THREADS;
        if (idx < K_TOT * 128) {
            int k = idx >> 7;
            int o = idx & 127;
            float v = (k < 128) ? WSw[o * 128 + k]
                    : (k < 256) ? WTw[o * 128 + (k - 128)]
                                : Tw[o * 64 + (k - 256)];
            Gtb[(size_t)o * K_TOT + k] = f2bf(v);
        }
        if (idx < 128) bias2[idx] = WTb[idx] + Tb[idx];
    }
}

// ---------------------------------------------------------------------------
// CSR build: scan -> fill ec[pos] = (col,e)
// fill bumps `offsets` in place; afterwards offsets[n] == end[n] and
// offsets[n-1] == beg[n] (CSR contiguity).
// ---------------------------------------------------------------------------
__global__ __launch_bounds__(256) void scan_pass1(const int* __restrict__ hist,
                                                  int* __restrict__ chunksum) {
    __shared__ int ts[256];
    int b = blockIdx.x, t = threadIdx.x;
    int i = b * 1024 + t * 4;
    int s = 0;
#pragma unroll
    for (int j = 0; j < 4; ++j)
        if (i + j < N_NODES) s += hist[i + j];
    ts[t] = s;
    __syncthreads();
    for (int off = 128; off > 0; off >>= 1) {
        if (t < off) ts[t] += ts[t + off];
        __syncthreads();
    }
    if (t == 0) chunksum[b] = ts[0];
}

__global__ __launch_bounds__(128) void scan_mid(const int* __restrict__ chunksum,
                                                int* __restrict__ chunkoff) {
    __shared__ int ts[128];
    int t = threadIdx.x;
    int v = (t < NCHUNK) ? chunksum[t] : 0;
    ts[t] = v;
    __syncthreads();
    for (int off = 1; off < 128; off <<= 1) {
        int a = (t >= off) ? ts[t - off] : 0;
        __syncthreads();
        ts[t] += a;
        __syncthreads();
    }
    if (t < NCHUNK) chunkoff[t] = ts[t] - v;   // exclusive
}

__global__ __launch_bounds__(256) void scan_pass2(const int* __restrict__ hist,
                                                  const int* __restrict__ chunkoff,
                                                  int* __restrict__ offsets) {
    __shared__ int ts[256];
    int b = blockIdx.x, t = threadIdx.x;
    int i0 = b * 1024 + t * 4;
    int v[4];
    int s = 0;
#pragma unroll
    for (int j = 0; j < 4; ++j) {
        v[j] = (i0 + j < N_NODES) ? hist[i0 + j] : 0;
        s += v[j];
    }
    ts[t] = s;
    __syncthreads();
    for (int off = 1; off < 256; off <<= 1) {
        int add = (t >= off) ? ts[t - off] : 0;
        __syncthreads();
        ts[t] += add;
        __syncthreads();
    }
    int run = chunkoff[b] + ts[t] - s;   // exclusive base for this thread
#pragma unroll
    for (int j = 0; j < 4; ++j) {
        if (i0 + j < N_NODES) offsets[i0 + j] = run;
        run += v[j];
    }
}

__global__ __launch_bounds__(256) void fill_kernel(const int* __restrict__ ei,
                                                   int* __restrict__ offsets,
                                                   unsigned long long* __restrict__ ec) {
    int e = blockIdx.x * 256 + threadIdx.x;
    if (e < N_EDGES) {
        int row = ei[e];
        int col = ei[N_EDGES + e];
        int pos = atomicAdd(&offsets[row], 1);
        ec[pos] = ((unsigned long long)(unsigned)col << 32) | (unsigned)e;
    }
}

// ---------------------------------------------------------------------------
// Segment reduce: one wave per node, 4 edges per iteration.
// Gathers xb (bf16, 4 B/lane -> 256 B/row, half the traffic of fp32 x);
// unpack is one shift. Accumulates fp32, emits bf16. tf stays fp32 (read
// exactly once -> no benefit converting). Remainder handled in one
// predicated step: clamped indices issue all gathers in parallel,
// wave-uniform rem branches are scalar (no divergence, no serial chain).
// ---------------------------------------------------------------------------
__global__ __launch_bounds__(256) void agg_kernel(
        const unsigned* __restrict__ xw,   // xb as u32 words, row stride 64
        const float* __restrict__ tf,
        const unsigned long long* __restrict__ ec,
        const int* __restrict__ offsets,   // post-fill: offsets[n] = end[n]
        unsigned* __restrict__ aggxb,      // u32 view: row stride 64 words (128 bf16)
        unsigned* __restrict__ aggtb,      // u32 view: row stride 32 words (64 bf16)
        float* __restrict__ deg) {
    int lane = threadIdx.x & 63;
    int n = blockIdx.x * 4 + (threadIdx.x >> 6);   // grid exact: n < N_NODES

    int beg = n ? offsets[n - 1] : 0;
    int end = offsets[n];

    float ax = 0.f, ay = 0.f, at = 0.f;
    float bx = 0.f, by = 0.f, bt = 0.f;

    int i = beg;
    for (; i + 3 < end; i += 4) {
        unsigned long long p0 = ec[i],     p1 = ec[i + 1];
        unsigned long long p2 = ec[i + 2], p3 = ec[i + 3];
        unsigned a = xw[((size_t)(p0 >> 32) << 6) + lane];
        unsigned b = xw[((size_t)(p1 >> 32) << 6) + lane];
        unsigned c = xw[((size_t)(p2 >> 32) << 6) + lane];
        unsigned d = xw[((size_t)(p3 >> 32) << 6) + lane];
        float u0 = __builtin_nontemporal_load(tf + ((size_t)(unsigned)p0 << 6) + lane);
        float u1 = __builtin_nontemporal_load(tf + ((size_t)(unsigned)p1 << 6) + lane);
        float u2 = __builtin_nontemporal_load(tf + ((size_t)(unsigned)p2 << 6) + lane);
        float u3 = __builtin_nontemporal_load(tf + ((size_t)(unsigned)p3 << 6) + lane);
        ax += bflo(a); ay += bfhi(a); at += u0;
        bx += bflo(b); by += bfhi(b); bt += u1;
        ax += bflo(c); ay += bfhi(c); at += u2;
        bx += bflo(d); by += bfhi(d); bt += u3;
    }
    int rem = end - i;                     // 0..3, wave-uniform
    if (rem) {
        unsigned long long p0 = ec[i];
        unsigned long long p1 = (rem > 1) ? ec[i + 1] : p0;
        unsigned long long p2 = (rem > 2) ? ec[i + 2] : p0;
        unsigned a = xw[((size_t)(p0 >> 32) << 6) + lane];
        unsigned b = xw[((size_t)(p1 >> 32) << 6) + lane];
        unsigned c = xw[((size_t)(p2 >> 32) << 6) + lane];
        float u0 = __builtin_nontemporal_load(tf + ((size_t)(unsigned)p0 << 6) + lane);
        float u1 = __builtin_nontemporal_load(tf + ((size_t)(unsigned)p1 << 6) + lane);
        float u2 = __builtin_nontemporal_load(tf + ((size_t)(unsigned)p2 << 6) + lane);
        ax += bflo(a); ay += bfhi(a); at += u0;
        if (rem > 1) { bx += bflo(b); by += bfhi(b); bt += u1; }
        if (rem > 2) { ax += bflo(c); ay += bfhi(c); at += u2; }
    }

    float fx = ax + bx, fy = ay + by, ft = at + bt;
    aggxb[(size_t)n * 64 + lane] = pack2(fx, fy);        // cols 2l, 2l+1
    float pt = __shfl_xor(ft, 1);
    if (!(lane & 1))
        aggtb[(size_t)n * 32 + (lane >> 1)] = pack2(ft, pt);  // cols l, l+1
    if (lane == 0) deg[n] = (float)(end - beg);
}

// ---------------------------------------------------------------------------
// MFMA bf16 GEMM: out = relu([xb | aggxb | aggtb] @ Gtb^T + WSb + deg*bias2)
// All operands pre-converted bf16 -> staging is a pure uint4 copy. Rows >=
// N_NODES read padded workspace garbage; their acc rows are never stored.
// ---------------------------------------------------------------------------
__global__ __launch_bounds__(256) void gemm_kernel(
        const unsigned short* __restrict__ xb,
        const unsigned short* __restrict__ aggxb,
        const unsigned short* __restrict__ aggtb,
        const unsigned short* __restrict__ Gtb,
        const float* __restrict__ WSb,
        const float* __restrict__ bias2,
        const float* __restrict__ deg,
        float* __restrict__ out) {
    __shared__ unsigned short As[BM * LDA];
    __shared__ unsigned short Bs[BM * LDA];

    int t = threadIdx.x;
    int lane = t & 63;
    int wave = t >> 6;
    int mw = (wave & 1) * 64;
    int nw = (wave >> 1) * 64;
    int row0 = blockIdx.x * BM;
    int quad = lane >> 4;
    int l16  = lane & 15;

    f32x4 acc[4][4];
#pragma unroll
    for (int mt = 0; mt < 4; ++mt)
#pragma unroll
        for (int nt = 0; nt < 4; ++nt)
            acc[mt][nt] = (f32x4){0.f, 0.f, 0.f, 0.f};

    int sm = t >> 1;            // staging row 0..127
    int sh = (t & 1) * 32;      // staging k-half offset (bf16 elems)

    for (int c = 0; c < 5; ++c) {
        const unsigned short* src; int ld, koff;
        if (c < 2)      { src = xb;    ld = 128; koff = c * 64; }
        else if (c < 4) { src = aggxb; ld = 128; koff = (c - 2) * 64; }
        else            { src = aggtb; ld = 64;  koff = 0; }

        // issue global loads before the barrier: overlap with prev MFMA
        const unsigned short* ap = src + (size_t)(row0 + sm) * ld + koff + sh;
        uint4 a0 = *(const uint4*)(ap);
        uint4 a1 = *(const uint4*)(ap + 8);
        uint4 a2 = *(const uint4*)(ap + 16);
        uint4 a3 = *(const uint4*)(ap + 24);
        const unsigned short* gp = Gtb + (size_t)sm * K_TOT + c * 64 + sh;
        uint4 b0 = *(const uint4*)(gp);
        uint4 b1 = *(const uint4*)(gp + 8);
        uint4 b2 = *(const uint4*)(gp + 16);
        uint4 b3 = *(const uint4*)(gp + 24);

        __syncthreads();        // previous iteration's LDS reads done

        *(uint4*)&As[sm * LDA + sh]      = a0;
        *(uint4*)&As[sm * LDA + sh + 8]  = a1;
        *(uint4*)&As[sm * LDA + sh + 16] = a2;
        *(uint4*)&As[sm * LDA + sh + 24] = a3;
        *(uint4*)&Bs[sm * LDA + sh]      = b0;
        *(uint4*)&Bs[sm * LDA + sh + 8]  = b1;
        *(uint4*)&Bs[sm * LDA + sh + 16] = b2;
        *(uint4*)&Bs[sm * LDA + sh + 24] = b3;

        __syncthreads();

#pragma unroll
        for (int ks = 0; ks < 2; ++ks) {
            bf16x8 af[4], bfv[4];
#pragma unroll
            for (int mt = 0; mt < 4; ++mt)
                af[mt] = *(bf16x8*)&As[(mw + mt * 16 + l16) * LDA + ks * 32 + quad * 8];
#pragma unroll
            for (int nt = 0; nt < 4; ++nt)
                bfv[nt] = *(bf16x8*)&Bs[(nw + nt * 16 + l16) * LDA + ks * 32 + quad * 8];
#pragma unroll
            for (int mt = 0; mt < 4; ++mt)
#pragma unroll
                for (int nt = 0; nt < 4; ++nt)
                    acc[mt][nt] = __builtin_amdgcn_mfma_f32_16x16x32_bf16(
                        af[mt], bfv[nt], acc[mt][nt], 0, 0, 0);
        }
    }

    // epilogue: bias + deg*bias2 + ReLU
#pragma unroll
    for (int mt = 0; mt < 4; ++mt) {
#pragma unroll
        for (int r = 0; r < 4; ++r) {
            int m = row0 + mw + mt * 16 + quad * 4 + r;
            if (m >= N_NODES) continue;
            float dg = deg[m];
#pragma unroll
            for (int nt = 0; nt < 4; ++nt) {
                int o = nw + nt * 16 + l16;
                float val = acc[mt][nt][r] + WSb[o] + dg * bias2[o];
                out[(size_t)m * 128 + o] = fmaxf(val, 0.f);
            }
        }
    }
}

// ---------------------------------------------------------------------------
extern "C" void kernel_launch(void* const* d_in, const int* in_sizes, int n_in,
                              void* d_out, int out_size, void* d_ws, size_t ws_size,
                              hipStream_t stream) {
    const float* x   = (const float*)d_in[0];
    const int*   ei  = (const int*)d_in[1];
    const float* tf  = (const float*)d_in[2];
    const float* WSw = (const float*)d_in[3];
    const float* WSb = (const float*)d_in[4];
    const float* WTw = (const float*)d_in[5];
    const float* WTb = (const float*)d_in[6];
    const float* Tw  = (const float*)d_in[7];
    const float* Tb  = (const float*)d_in[8];
    float* out = (float*)d_out;

    // Workspace layout (~73.4 MB), 16B-aligned blocks first:
    unsigned short* xb    = (unsigned short*)d_ws;                 // M_PAD*128 bf16
    unsigned short* aggxb = xb    + (size_t)M_PAD * 128;           // M_PAD*128 bf16
    unsigned short* aggtb = aggxb + (size_t)M_PAD * 128;           // M_PAD*64  bf16
    unsigned short* Gtb   = aggtb + (size_t)M_PAD * 64;            // 320*128   bf16
    unsigned long long* ec = (unsigned long long*)(Gtb + (size_t)K_TOT * 128); // 1M u64
    float* deg   = (float*)(ec + N_EDGES);                         // 100000 f
    float* bias2 = deg + N_NODES;                                  // 128 f
    int* hist    = (int*)(bias2 + 128);                            // 100000 i
    int* offsets = hist + N_NODES;                                 // 100002 i
    int* csum    = offsets + (N_NODES + 2);                        // 128 i
    int* coff    = csum + 128;                                     // 128 i

    hipMemsetAsync(hist, 0, (size_t)N_NODES * sizeof(int), stream);

    prep_hist_kernel<<<PREP_BLOCKS + HIST_BLOCKS, 256, 0, stream>>>(
        x, WSw, WTw, Tw, WTb, Tb, xb, Gtb, bias2, ei, hist);

    scan_pass1<<<NCHUNK, 256, 0, stream>>>(hist, csum);
    scan_mid<<<1, 128, 0, stream>>>(csum, coff);
    scan_pass2<<<NCHUNK, 256, 0, stream>>>(hist, coff, offsets);

    fill_kernel<<<(N_EDGES + 255) / 256, 256, 0, stream>>>(ei, offsets, ec);

    agg_kernel<<<N_NODES / 4, 256, 0, stream>>>(
        (const unsigned*)xb, tf, ec, offsets, (unsigned*)aggxb, (unsigned*)aggtb, deg);

    gemm_kernel<<<(N_NODES + BM - 1) / BM, 256, 0, stream>>>(
        xb, aggxb, aggtb, Gtb, WSb, bias2, deg, out);
}

// Round 3
// 575.412 us; speedup vs baseline: 1.0897x; 1.0008x over previous
//
#include <hip/hip_runtime.h>

#define N_NODES 100000
#define M_PAD   100096      // N_NODES rounded up to BM multiple (pad rows: garbage, never stored)
#define N_EDGES 1000000
#define K_TOT   320         // 128 (x) + 128 (agg_x) + 64 (agg_t)
#define NCHUNK  98          // ceil(100000/1024)

#define BM  128

#define XCONV_THREADS 1600000          // N_NODES*128/8 elems, 8 per thread
#define PREP_BLOCKS   6410             // (XCONV_THREADS + K_TOT*128)/256
#define HIST_BLOCKS   3907             // ceil(N_EDGES/256)

typedef __attribute__((ext_vector_type(8))) short bf16x8;
typedef __attribute__((ext_vector_type(4))) float f32x4;

__device__ __forceinline__ unsigned short f2bf(float f) {
    unsigned u = __float_as_uint(f);
    u += 0x7FFFu + ((u >> 16) & 1u);          // round-to-nearest-even
    return (unsigned short)(u >> 16);
}
__device__ __forceinline__ unsigned pack2(float a, float b) {
    return (unsigned)f2bf(a) | ((unsigned)f2bf(b) << 16);
}
__device__ __forceinline__ float bflo(unsigned v) { return __uint_as_float(v << 16); }
__device__ __forceinline__ float bfhi(unsigned v) { return __uint_as_float(v & 0xffff0000u); }

// global -> LDS direct DMA, 16 B per lane. Dest = wave-uniform base + lane*16.
__device__ __forceinline__ void gl_lds16(const void* g, void* l) {
    __builtin_amdgcn_global_load_lds(
        (const __attribute__((address_space(1))) unsigned*)g,
        (__attribute__((address_space(3))) unsigned*)l, 16, 0, 0);
}

// ---------------------------------------------------------------------------
// Fused prep + hist:
//   blocks [0, PREP_BLOCKS):  xb = bf16(x), Gtb[o][k] k-contig bf16, bias2
//   blocks [PREP_BLOCKS, +HIST_BLOCKS): edge histogram (hist pre-zeroed)
// ---------------------------------------------------------------------------
__global__ __launch_bounds__(256) void prep_hist_kernel(
        const float* __restrict__ x,
        const float* __restrict__ WSw,
        const float* __restrict__ WTw,
        const float* __restrict__ Tw,
        const float* __restrict__ WTb,
        const float* __restrict__ Tb,
        unsigned short* __restrict__ xb,
        unsigned short* __restrict__ Gtb,
        float* __restrict__ bias2,
        const int* __restrict__ ei,
        int* __restrict__ hist) {
    int b = blockIdx.x;
    int t = threadIdx.x;
    if (b >= PREP_BLOCKS) {
        int e = (b - PREP_BLOCKS) * 256 + t;
        if (e < N_EDGES) atomicAdd(&hist[ei[e]], 1);
        return;
    }
    int gid = b * 256 + t;
    if (gid < XCONV_THREADS) {
        const float4* p = (const float4*)x + (size_t)gid * 2;
        float4 u0 = p[0], u1 = p[1];
        uint4 w;
        w.x = pack2(u0.x, u0.y);
        w.y = pack2(u0.z, u0.w);
        w.z = pack2(u1.x, u1.y);
        w.w = pack2(u1.z, u1.w);
        *(uint4*)(xb + (size_t)gid * 8) = w;
    } else {
        int idx = gid - XCONV_THREADS;
        if (idx < K_TOT * 128) {
            int k = idx >> 7;
            int o = idx & 127;
            float v = (k < 128) ? WSw[o * 128 + k]
                    : (k < 256) ? WTw[o * 128 + (k - 128)]
                                : Tw[o * 64 + (k - 256)];
            Gtb[(size_t)o * K_TOT + k] = f2bf(v);
        }
        if (idx < 128) bias2[idx] = WTb[idx] + Tb[idx];
    }
}

// ---------------------------------------------------------------------------
// CSR build: scan (2 kernels; chunk-prefix folded into pass2) -> fill.
// fill bumps `offsets` in place; afterwards offsets[n] == end[n] and
// offsets[n-1] == beg[n] (CSR contiguity).
// ---------------------------------------------------------------------------
__global__ __launch_bounds__(256) void scan_pass1(const int* __restrict__ hist,
                                                  int* __restrict__ chunksum) {
    __shared__ int ts[256];
    int b = blockIdx.x, t = threadIdx.x;
    int i = b * 1024 + t * 4;
    int s = 0;
#pragma unroll
    for (int j = 0; j < 4; ++j)
        if (i + j < N_NODES) s += hist[i + j];
    ts[t] = s;
    __syncthreads();
    for (int off = 128; off > 0; off >>= 1) {
        if (t < off) ts[t] += ts[t + off];
        __syncthreads();
    }
    if (t == 0) chunksum[b] = ts[0];
}

__global__ __launch_bounds__(256) void scan_pass2(const int* __restrict__ hist,
                                                  const int* __restrict__ csum,
                                                  int* __restrict__ offsets) {
    __shared__ int ts[256];
    __shared__ int cbase_s;
    int b = blockIdx.x, t = threadIdx.x;
    int i0 = b * 1024 + t * 4;
    int v[4];
    int s = 0;
#pragma unroll
    for (int j = 0; j < 4; ++j) {
        v[j] = (i0 + j < N_NODES) ? hist[i0 + j] : 0;
        s += v[j];
    }
    ts[t] = s;
    // wave 0: exclusive chunk base = sum csum[0..b)  (<=2 loads/lane, L2-hot)
    if (t < 64) {
        int cs = 0;
        for (int i = t; i < b; i += 64) cs += csum[i];
        for (int off = 32; off; off >>= 1) cs += __shfl_down(cs, off);
        if (t == 0) cbase_s = cs;
    }
    __syncthreads();
    for (int off = 1; off < 256; off <<= 1) {
        int add = (t >= off) ? ts[t - off] : 0;
        __syncthreads();
        ts[t] += add;
        __syncthreads();
    }
    int run = cbase_s + ts[t] - s;   // exclusive base for this thread
#pragma unroll
    for (int j = 0; j < 4; ++j) {
        if (i0 + j < N_NODES) offsets[i0 + j] = run;
        run += v[j];
    }
}

__global__ __launch_bounds__(256) void fill_kernel(const int* __restrict__ ei,
                                                   int* __restrict__ offsets,
                                                   unsigned long long* __restrict__ ec) {
    int e = blockIdx.x * 256 + threadIdx.x;
    if (e < N_EDGES) {
        int row = ei[e];
        int col = ei[N_EDGES + e];
        int pos = atomicAdd(&offsets[row], 1);
        ec[pos] = ((unsigned long long)(unsigned)col << 32) | (unsigned)e;
    }
}

// ---------------------------------------------------------------------------
// Segment reduce: one wave per node, 8 edges per iteration (deep MLP), 4
// independent accumulator triples. Remainder (0..7) fully predicated with
// clamped indices: all gathers issue in parallel, dup loads are L1 hits,
// rem branches are wave-uniform (scalar).
// ---------------------------------------------------------------------------
__global__ __launch_bounds__(256) void agg_kernel(
        const unsigned* __restrict__ xw,   // xb as u32 words, row stride 64
        const float* __restrict__ tf,
        const unsigned long long* __restrict__ ec,
        const int* __restrict__ offsets,   // post-fill: offsets[n] = end[n]
        unsigned* __restrict__ aggxb,      // u32 view: row stride 64 words (128 bf16)
        unsigned* __restrict__ aggtb,      // u32 view: row stride 32 words (64 bf16)
        float* __restrict__ deg) {
    int lane = threadIdx.x & 63;
    int n = blockIdx.x * 4 + (threadIdx.x >> 6);   // grid exact: n < N_NODES

    int beg = n ? offsets[n - 1] : 0;
    int end = offsets[n];

    float ax[4] = {0.f, 0.f, 0.f, 0.f};
    float ay[4] = {0.f, 0.f, 0.f, 0.f};
    float at[4] = {0.f, 0.f, 0.f, 0.f};

    int i = beg;
    for (; i + 7 < end; i += 8) {
        unsigned long long p[8];
#pragma unroll
        for (int j = 0; j < 8; ++j) p[j] = ec[i + j];
        unsigned xv[8];
        float tv[8];
#pragma unroll
        for (int j = 0; j < 8; ++j)
            xv[j] = xw[((size_t)(p[j] >> 32) << 6) + lane];
#pragma unroll
        for (int j = 0; j < 8; ++j)
            tv[j] = __builtin_nontemporal_load(tf + ((size_t)(unsigned)p[j] << 6) + lane);
#pragma unroll
        for (int j = 0; j < 8; ++j) {
            ax[j & 3] += bflo(xv[j]);
            ay[j & 3] += bfhi(xv[j]);
            at[j & 3] += tv[j];
        }
    }
    int rem = end - i;                     // 0..7, wave-uniform
    if (rem) {
        int last = end - 1;
        unsigned long long p[8];
#pragma unroll
        for (int j = 0; j < 8; ++j) {
            int idx = i + j;
            if (idx > last) idx = last;
            p[j] = ec[idx];
        }
        unsigned xv[8];
        float tv[8];
#pragma unroll
        for (int j = 0; j < 8; ++j)
            xv[j] = xw[((size_t)(p[j] >> 32) << 6) + lane];
#pragma unroll
        for (int j = 0; j < 8; ++j)
            tv[j] = __builtin_nontemporal_load(tf + ((size_t)(unsigned)p[j] << 6) + lane);
#pragma unroll
        for (int j = 0; j < 8; ++j) {
            if (j < rem) {
                ax[j & 3] += bflo(xv[j]);
                ay[j & 3] += bfhi(xv[j]);
                at[j & 3] += tv[j];
            }
        }
    }

    float fx = (ax[0] + ax[1]) + (ax[2] + ax[3]);
    float fy = (ay[0] + ay[1]) + (ay[2] + ay[3]);
    float ft = (at[0] + at[1]) + (at[2] + at[3]);
    aggxb[(size_t)n * 64 + lane] = pack2(fx, fy);        // cols 2l, 2l+1
    float pt = __shfl_xor(ft, 1);
    if (!(lane & 1))
        aggtb[(size_t)n * 32 + (lane >> 1)] = pack2(ft, pt);  // cols l, l+1
    if (lane == 0) deg[n] = (float)(end - beg);
}

// ---------------------------------------------------------------------------
// MFMA bf16 GEMM: out = relu([xb | aggxb | aggtb] @ Gtb^T + WSb + deg*bias2)
// Staging via global_load_lds width=16 (no VGPR round-trip). LDS is linear
// (no pad); bank conflicts avoided with XOR swizzle byte ^= ((row&7)<<4),
// realized by pre-swizzling the per-lane GLOBAL source address (linear dest
// + inverse-swizzled source + swizzled read). Pad rows (>=N_NODES) read
// workspace garbage; their acc rows are never stored.
// ---------------------------------------------------------------------------
__global__ __launch_bounds__(256) void gemm_kernel(
        const unsigned short* __restrict__ xb,
        const unsigned short* __restrict__ aggxb,
        const unsigned short* __restrict__ aggtb,
        const unsigned short* __restrict__ Gtb,
        const float* __restrict__ WSb,
        const float* __restrict__ bias2,
        const float* __restrict__ deg,
        float* __restrict__ out) {
    __shared__ unsigned short As[BM * 64];   // 16 KB, swizzled content
    __shared__ unsigned short Bs[BM * 64];   // 16 KB

    int t = threadIdx.x;
    int lane = t & 63;
    int wave = t >> 6;
    int mw = (wave & 1) * 64;
    int nw = (wave >> 1) * 64;
    int row0 = blockIdx.x * BM;
    int quad = lane >> 4;
    int l16  = lane & 15;

    // staging geometry: region r = wave*4 + j covers LDS rows 8r..8r+8.
    // lane: lr = row-in-region (0..7), lc = 16B-slot (0..7); source col is
    // XOR-swizzled so a swizzled read finds linear data.
    int lr = lane >> 3;
    int lc = lane & 7;
    int swz = ((lc ^ lr) << 4);              // byte offset within 128-B row

    f32x4 acc[4][4];
#pragma unroll
    for (int mt = 0; mt < 4; ++mt)
#pragma unroll
        for (int nt = 0; nt < 4; ++nt)
            acc[mt][nt] = (f32x4){0.f, 0.f, 0.f, 0.f};

    for (int c = 0; c < 5; ++c) {
        const char* srcA; size_t ldb, koffb;
        if (c < 2)      { srcA = (const char*)xb;    ldb = 256; koffb = (size_t)c * 128; }
        else if (c < 4) { srcA = (const char*)aggxb; ldb = 256; koffb = (size_t)(c - 2) * 128; }
        else            { srcA = (const char*)aggtb; ldb = 128; koffb = 0; }

        __syncthreads();        // previous chunk's LDS reads done
#pragma unroll
        for (int j = 0; j < 4; ++j) {
            int r = wave * 4 + j;
            int row = r * 8 + lr;
            gl_lds16(srcA + (size_t)(row0 + row) * ldb + koffb + swz,
                     (char*)As + r * 1024);
            gl_lds16((const char*)Gtb + (size_t)row * 640 + (size_t)c * 128 + swz,
                     (char*)Bs + r * 1024);
        }
        __syncthreads();        // barrier drains vmcnt -> LDS ready

#pragma unroll
        for (int ks = 0; ks < 2; ++ks) {
            bf16x8 af[4], bfv[4];
            int rb = ((ks * 64 + quad * 16) ^ ((l16 & 7) << 4));
#pragma unroll
            for (int mt = 0; mt < 4; ++mt)
                af[mt] = *(const bf16x8*)((const char*)As + (mw + mt * 16 + l16) * 128 + rb);
#pragma unroll
            for (int nt = 0; nt < 4; ++nt)
                bfv[nt] = *(const bf16x8*)((const char*)Bs + (nw + nt * 16 + l16) * 128 + rb);
#pragma unroll
            for (int mt = 0; mt < 4; ++mt)
#pragma unroll
                for (int nt = 0; nt < 4; ++nt)
                    acc[mt][nt] = __builtin_amdgcn_mfma_f32_16x16x32_bf16(
                        af[mt], bfv[nt], acc[mt][nt], 0, 0, 0);
        }
    }

    // epilogue: bias + deg*bias2 + ReLU, nontemporal (out never re-read)
    float wsb[4], b2[4];
#pragma unroll
    for (int nt = 0; nt < 4; ++nt) {
        int o = nw + nt * 16 + l16;
        wsb[nt] = WSb[o];
        b2[nt]  = bias2[o];
    }
#pragma unroll
    for (int mt = 0; mt < 4; ++mt) {
#pragma unroll
        for (int r = 0; r < 4; ++r) {
            int m = row0 + mw + mt * 16 + quad * 4 + r;
            if (m >= N_NODES) continue;
            float dg = deg[m];
#pragma unroll
            for (int nt = 0; nt < 4; ++nt) {
                int o = nw + nt * 16 + l16;
                float val = acc[mt][nt][r] + wsb[nt] + dg * b2[nt];
                __builtin_nontemporal_store(fmaxf(val, 0.f), &out[(size_t)m * 128 + o]);
            }
        }
    }
}

// ---------------------------------------------------------------------------
extern "C" void kernel_launch(void* const* d_in, const int* in_sizes, int n_in,
                              void* d_out, int out_size, void* d_ws, size_t ws_size,
                              hipStream_t stream) {
    const float* x   = (const float*)d_in[0];
    const int*   ei  = (const int*)d_in[1];
    const float* tf  = (const float*)d_in[2];
    const float* WSw = (const float*)d_in[3];
    const float* WSb = (const float*)d_in[4];
    const float* WTw = (const float*)d_in[5];
    const float* WTb = (const float*)d_in[6];
    const float* Tw  = (const float*)d_in[7];
    const float* Tb  = (const float*)d_in[8];
    float* out = (float*)d_out;

    // Workspace layout (~73.4 MB), 16B-aligned blocks first:
    unsigned short* xb    = (unsigned short*)d_ws;                 // M_PAD*128 bf16
    unsigned short* aggxb = xb    + (size_t)M_PAD * 128;           // M_PAD*128 bf16
    unsigned short* aggtb = aggxb + (size_t)M_PAD * 128;           // M_PAD*64  bf16
    unsigned short* Gtb   = aggtb + (size_t)M_PAD * 64;            // 320*128   bf16
    unsigned long long* ec = (unsigned long long*)(Gtb + (size_t)K_TOT * 128); // 1M u64
    float* deg   = (float*)(ec + N_EDGES);                         // 100000 f
    float* bias2 = deg + N_NODES;                                  // 128 f
    int* hist    = (int*)(bias2 + 128);                            // 100000 i
    int* offsets = hist + N_NODES;                                 // 100002 i
    int* csum    = offsets + (N_NODES + 2);                        // 128 i

    hipMemsetAsync(hist, 0, (size_t)N_NODES * sizeof(int), stream);

    prep_hist_kernel<<<PREP_BLOCKS + HIST_BLOCKS, 256, 0, stream>>>(
        x, WSw, WTw, Tw, WTb, Tb, xb, Gtb, bias2, ei, hist);

    scan_pass1<<<NCHUNK, 256, 0, stream>>>(hist, csum);
    scan_pass2<<<NCHUNK, 256, 0, stream>>>(hist, csum, offsets);

    fill_kernel<<<(N_EDGES + 255) / 256, 256, 0, stream>>>(ei, offsets, ec);

    agg_kernel<<<N_NODES / 4, 256, 0, stream>>>(
        (const unsigned*)xb, tf, ec, offsets, (unsigned*)aggxb, (unsigned*)aggtb, deg);

    gemm_kernel<<<(N_NODES + BM - 1) / BM, 256, 0, stream>>>(
        xb, aggxb, aggtb, Gtb, WSb, bias2, deg, out);
}